// Round 6
// baseline (89.604 us; speedup 1.0000x reference)
//
#include <hip/hip_runtime.h>
#include <cmath>

#define HH 512
#define WW 512
// one wave (64 threads) owns a 64-wide x 16-tall output tile
#define SW   68          // column stride (floats) for all LDS buffers
#define HB_R 24          // hblur rows  (16 + 2*4)
#define BL_R 20          // blurred rows (16 + 2*2)
#define MG_R 18          // mag rows    (16 + 2*1)  -- aliases hb buffer
#define LDS_FLOATS (HB_R*SW + BL_R*SW + 8)   // hb + bl + pad (12.0 KB)

struct Blur5 { float w[5]; };

// packed (dr+1),(dc+1) 2-bit LUTs for the 8 NMS directions
// OFFS = {(0,1),(-1,1),(-1,0),(-1,-1),(0,-1),(1,-1),(1,0),(1,1)}
#define DR_PACK 43265u
#define DC_PACK 36890u

__device__ __forceinline__ float4 ld4(const float* p) {
  return *reinterpret_cast<const float4*>(p);
}
__device__ __forceinline__ void st4(float* p, float4 v) {
  *reinterpret_cast<float4*>(p) = v;
}

// rc = jnp.round((degrees(atan2(gy,gx)) + 180)/45) in [0,8], via comparisons.
// Validated vs reference in R1-R4 (absmax 0.0).
__device__ __forceinline__ int orient_bin(float gx, float gy) {
  const float T1 = 0.41421356237309503f;  // tan(22.5)
  const float T2 = 2.41421356237309503f;  // tan(67.5)
  float a = fabsf(gy), b = fabsf(gx);
  int sx = (int)(__float_as_uint(gx) >> 31);
  int sy = (int)(__float_as_uint(gy) >> 31);
  int rc;
  if (a <= T1 * b)      rc = sx ? (8 - 8 * sy) : 4;
  else if (a >= T2 * b) rc = 6 - 4 * sy;
  else                  rc = sx ? (7 - 6 * sy) : (5 - 2 * sy);
  return rc;
}

// Per-wave canny over a 64x16 tile. No __syncthreads anywhere: a single wave's
// DS ops execute in order, and the compiler inserts lgkmcnt waits for RAW deps.
// ACC=false: store thin/rc.  ACC=true: accumulate loss vs stored arrays.
template<bool ACC>
__device__ __forceinline__ void canny_wave_tile(
    const float* __restrict__ img, int base_r, int base_c,
    float* __restrict__ hb, float* __restrict__ bl, const Blur5& kb,
    float thin[16], int rcv[16], float& sAcc, int& soAcc)
{
  const int lane = threadIdx.x;   // 0..63
  const float k0 = kb.w[0], k1 = kb.w[1], k2 = kb.w[2], k3 = kb.w[3], k4 = kb.w[4];
  float* mg = hb;                 // mag buffer aliases hblur (hb dead after vblur)

  // ---- A: fused stage+hblur -> hb[24][68] ----
  // hb[hr][hc] = hblur at image (base_r+hr-4, base_c+hc-2).
  // Output group hc=4k..4k+3 needs image cols base_c+4k-4 .. +3 = 2 aligned ld4.
  for (int g = lane; g < HB_R * 17; g += 64) {
    int hr = g / 17, k = g - hr * 17;
    int gr = base_r + hr - 4;
    int gcb = base_c + k * 4 - 4;
    float e0=0.f,e1=0.f,e2=0.f,e3=0.f,e4=0.f,e5=0.f,e6=0.f,e7=0.f;
    bool rok = (unsigned)gr < HH;
    if (rok && (unsigned)gcb < WW) {
      float4 a = ld4(img + gr * WW + gcb);
      e0=a.x; e1=a.y; e2=a.z; e3=a.w;
    }
    if (rok && (unsigned)(gcb + 4) < WW) {
      float4 b = ld4(img + gr * WW + gcb + 4);
      e4=b.x; e5=b.y; e6=b.z; e7=b.w;
    }
    float4 o;
    o.x = k0*e0 + k1*e1 + k2*e2 + k3*e3 + k4*e4;
    o.y = k0*e1 + k1*e2 + k2*e3 + k3*e4 + k4*e5;
    o.z = k0*e2 + k1*e3 + k2*e4 + k3*e5 + k4*e6;
    o.w = k0*e3 + k1*e4 + k2*e5 + k3*e6 + k4*e7;
    st4(&hb[hr * SW + k * 4], o);
  }

  // ---- B: vertical blur -> bl[20][68]; zero outside image ----
  // bl[br][hc] = blurred at image (base_r+br-2, base_c+hc-2).
  for (int g = lane; g < BL_R * 17; g += 64) {
    int br = g / 17, k = g - br * 17, c4 = k * 4;
    const float* p = &hb[br * SW + c4];
    float4 v0 = ld4(p), v1 = ld4(p + SW), v2 = ld4(p + 2*SW),
           v3 = ld4(p + 3*SW), v4 = ld4(p + 4*SW);
    float4 o;
    o.x = k0*v0.x + k1*v1.x + k2*v2.x + k3*v3.x + k4*v4.x;
    o.y = k0*v0.y + k1*v1.y + k2*v2.y + k3*v3.y + k4*v4.y;
    o.z = k0*v0.z + k1*v1.z + k2*v2.z + k3*v3.z + k4*v4.z;
    o.w = k0*v0.w + k1*v1.w + k2*v2.w + k3*v3.w + k4*v4.w;
    bool rok = (unsigned)(base_r + br - 2) < HH;
    int gcb = base_c + c4 - 2;
    o.x = (rok && (unsigned)(gcb + 0) < WW) ? o.x : 0.f;
    o.y = (rok && (unsigned)(gcb + 1) < WW) ? o.y : 0.f;
    o.z = (rok && (unsigned)(gcb + 2) < WW) ? o.z : 0.f;
    o.w = (rok && (unsigned)(gcb + 3) < WW) ? o.w : 0.f;
    st4(&bl[br * SW + c4], o);
  }

  // ---- C: sobel magnitude -> mg[18][68] (aliases hb); zero outside ----
  // mg[mr][c] = mag at image (base_r+mr-1, base_c+c-1), from bl cols c..c+2.
  for (int g = lane; g < MG_R * 17; g += 64) {
    int mr = g / 17, k = g - mr * 17, c4 = k * 4;
    const float* p = &bl[mr * SW + c4];
    float4 a0 = ld4(p),          b0 = ld4(p + 4);
    float4 a1 = ld4(p + SW),     b1 = ld4(p + SW + 4);
    float4 a2 = ld4(p + 2*SW),   b2 = ld4(p + 2*SW + 4);
    float e0[6] = {a0.x,a0.y,a0.z,a0.w,b0.x,b0.y};
    float e1[6] = {a1.x,a1.y,a1.z,a1.w,b1.x,b1.y};
    float e2[6] = {a2.x,a2.y,a2.z,a2.w,b2.x,b2.y};
    bool rok = (unsigned)(base_r + mr - 1) < HH;
    int gcb = base_c + c4 - 1;
    float4 o;
    float* po = &o.x;
    #pragma unroll
    for (int j = 0; j < 4; ++j) {
      float gx = (e0[j+2]-e0[j]) + 2.f*(e1[j+2]-e1[j]) + (e2[j+2]-e2[j]);
      float gy = (e2[j]-e0[j]) + 2.f*(e2[j+1]-e0[j+1]) + (e2[j+2]-e0[j+2]);
      float m = sqrtf(gx*gx + gy*gy + 1e-12f);
      po[j] = (rok && (unsigned)(gcb + j) < WW) ? m : 0.f;
    }
    st4(&mg[mr * SW + c4], o);
  }

  // ---- D: orientation bin + NMS, column-per-lane (conflict-free) ----
  // center row i -> bl rows i+1..i+3, mg row i+1; center col = lane.
  {
    float w00,w01,w02, w10,w11,w12, w20,w21,w22;
    {
      const float* p = &bl[1 * SW + lane + 1];
      w00 = p[0]; w01 = p[1]; w02 = p[2]; p += SW;
      w10 = p[0]; w11 = p[1]; w12 = p[2]; p += SW;
      w20 = p[0]; w21 = p[1]; w22 = p[2];
    }
    #pragma unroll
    for (int i = 0; i < 16; ++i) {
      float gx = (w02 - w00) + 2.f*(w12 - w10) + (w22 - w20);
      float gy = (w20 - w00) + 2.f*(w21 - w01) + (w22 - w02);
      int rc = orient_bin(gx, gy);
      int ip = rc & 7;
      int dr = (int)((DR_PACK >> (2 * ip)) & 3u) - 1;
      int dc = (int)((DC_PACK >> (2 * ip)) & 3u) - 1;
      int ci = (i + 1) * SW + lane + 1;
      float mcv = mg[ci];
      float n1  = mg[ci + dr * SW + dc];
      float n2  = mg[ci - dr * SW - dc];
      float th = (fminf(mcv - n1, mcv - n2) > 0.f) ? mcv : 0.f;
      if (ACC) {
        sAcc += fabsf(thin[i] - th);
        soAcc += abs(rcv[i] - rc);
      } else {
        thin[i] = th;
        rcv[i] = rc;
      }
      if (i < 15) {   // slide 3x3 window down one row
        const float* p = &bl[(i + 4) * SW + lane + 1];
        w00 = w10; w01 = w11; w02 = w12;
        w10 = w20; w11 = w21; w12 = w22;
        w20 = p[0]; w21 = p[1]; w22 = p[2];
      }
    }
  }
}

__global__ void __launch_bounds__(64)
canny_loss_kernel(const float* __restrict__ X, const float* __restrict__ Y,
                  float* __restrict__ out, Blur5 kb)
{
  __shared__ float lds[LDS_FLOATS];
  float* hb = lds;
  float* bl = lds + HB_R * SW;

  // grid: 4096 blocks = 16 batch x 32 row-tiles x 8 col-tiles
  const int idx = blockIdx.x;
  const int b  = idx >> 8;
  const int tr = (idx >> 3) & 31;
  const int tc = idx & 7;
  const int base_r = tr * 16;
  const int base_c = tc * 64;
  const float* xb = X + (size_t)b * HH * WW;
  const float* yb = Y + (size_t)b * HH * WW;

  float thin_x[16]; int rc_x[16];
  float s = 0.f; int so = 0;
  canny_wave_tile<false>(xb, base_r, base_c, hb, bl, kb, thin_x, rc_x, s, so);
  canny_wave_tile<true >(yb, base_r, base_c, hb, bl, kb, thin_x, rc_x, s, so);
  s += 45.f * (float)so;

  // single-wave reduction, one fire-and-forget atomic per block
  #pragma unroll
  for (int off = 32; off >= 1; off >>= 1) s += __shfl_down(s, off, 64);
  if (threadIdx.x == 0)
    atomicAdd(out, s * (1.0f / ((float)HH * (float)WW)));
}

extern "C" void kernel_launch(void* const* d_in, const int* in_sizes, int n_in,
                              void* d_out, int out_size, void* d_ws, size_t ws_size,
                              hipStream_t stream)
{
  const float* X = (const float*)d_in[0];
  const float* Y = (const float*)d_in[1];
  float* out = (float*)d_out;

  hipMemsetAsync(out, 0, (size_t)out_size * sizeof(float), stream);

  // Gaussian 1D weights in double, cast to f32 (matches reference f64->f32 path)
  Blur5 kb;
  {
    double g[5], ssum = 0.0;
    for (int i = 0; i < 5; ++i) { double d = i - 2; g[i] = std::exp(-(d * d) / 2.0); ssum += g[i]; }
    for (int i = 0; i < 5; ++i) kb.w[i] = (float)(g[i] / ssum);
  }

  canny_loss_kernel<<<4096, 64, 0, stream>>>(X, Y, out, kb);
}

// Round 7
// 53.341 us; speedup vs baseline: 1.6798x; 1.6798x over previous
//
#include <hip/hip_runtime.h>
#include <cmath>

#define HH 512
#define WW 512
#define TW 64      // tile width (output cols per block)
#define TH 32      // tile height (output rows per block)
#define SW 68      // column stride (floats), 272B, 16B-aligned
#define HB_R 40    // hblur rows  = TH + 2*4
#define BL_R 36    // blurred rows = TH + 2*2
#define MG_R 34    // mag rows     = TH + 2*1   (aliases hb)
#define NT 256

struct Blur5 { float w[5]; };

// packed (dr+1),(dc+1) 2-bit LUTs for the 8 NMS directions
// OFFS = {(0,1),(-1,1),(-1,0),(-1,-1),(0,-1),(1,-1),(1,0),(1,1)}
#define DR_PACK 43265u
#define DC_PACK 36890u

__device__ __forceinline__ float4 ld4(const float* p) {
  return *reinterpret_cast<const float4*>(p);
}
__device__ __forceinline__ void st4(float* p, float4 v) {
  *reinterpret_cast<float4*>(p) = v;
}

// rc = jnp.round((degrees(atan2(gy,gx)) + 180)/45) in [0,8], via comparisons.
// Validated vs reference R1-R5 (absmax 0.0).
__device__ __forceinline__ int orient_bin(float gx, float gy) {
  const float T1 = 0.41421356237309503f;  // tan(22.5)
  const float T2 = 2.41421356237309503f;  // tan(67.5)
  float a = fabsf(gy), b = fabsf(gx);
  int sx = (int)(__float_as_uint(gx) >> 31);
  int sy = (int)(__float_as_uint(gy) >> 31);
  int rc;
  if (a <= T1 * b)      rc = sx ? (8 - 8 * sy) : 4;
  else if (a >= T2 * b) rc = 6 - 4 * sy;
  else                  rc = sx ? (7 - 6 * sy) : (5 - 2 * sy);
  return rc;
}

__global__ void __launch_bounds__(NT)
canny_loss_kernel(const float* __restrict__ X, const float* __restrict__ Y,
                  float* __restrict__ out, Blur5 kb)
{
  __shared__ float hbX[HB_R * SW];
  __shared__ float hbY[HB_R * SW];
  __shared__ float blX[BL_R * SW];
  __shared__ float blY[BL_R * SW];
  __shared__ float red[NT / 64];
  float* mgX = hbX;   // mag aliases hblur (dead after vblur)
  float* mgY = hbY;

  // grid: 2048 blocks = 16 batch x 16 row-tiles x 8 col-tiles
  const int idx = blockIdx.x;
  const int b  = idx >> 7;
  const int tr = (idx >> 3) & 15;
  const int tc = idx & 7;
  const int base_r = tr * TH;
  const int base_c = tc * TW;
  const float* xb = X + (size_t)b * HH * WW;
  const float* yb = Y + (size_t)b * HH * WW;

  const int tid = threadIdx.x;
  const float k0 = kb.w[0], k1 = kb.w[1], k2 = kb.w[2], k3 = kb.w[3], k4 = kb.w[4];

  // ---- A: fused stage+hblur, both images -> hb[40][68] ----
  // hb[hr][hc] = hblur at image (base_r+hr-4, base_c+hc-2).
  for (int g = tid; g < HB_R * 17; g += NT) {
    int hr = g / 17, k = g - hr * 17;
    int gr = base_r + hr - 4;
    int gcb = base_c + k * 4 - 4;
    bool rok = (unsigned)gr < HH;
    bool ok0 = rok && (unsigned)gcb < WW;
    bool ok1 = rok && (unsigned)(gcb + 4) < WW;
    const float* px = xb + gr * WW + gcb;
    const float* py = yb + gr * WW + gcb;
    float4 xa = {0,0,0,0}, xbv = {0,0,0,0}, ya = {0,0,0,0}, ybv = {0,0,0,0};
    if (ok0) { xa = ld4(px); ya = ld4(py); }
    if (ok1) { xbv = ld4(px + 4); ybv = ld4(py + 4); }
    float4 ox, oy;
    ox.x = k0*xa.x + k1*xa.y + k2*xa.z + k3*xa.w + k4*xbv.x;
    ox.y = k0*xa.y + k1*xa.z + k2*xa.w + k3*xbv.x + k4*xbv.y;
    ox.z = k0*xa.z + k1*xa.w + k2*xbv.x + k3*xbv.y + k4*xbv.z;
    ox.w = k0*xa.w + k1*xbv.x + k2*xbv.y + k3*xbv.z + k4*xbv.w;
    oy.x = k0*ya.x + k1*ya.y + k2*ya.z + k3*ya.w + k4*ybv.x;
    oy.y = k0*ya.y + k1*ya.z + k2*ya.w + k3*ybv.x + k4*ybv.y;
    oy.z = k0*ya.z + k1*ya.w + k2*ybv.x + k3*ybv.y + k4*ybv.z;
    oy.w = k0*ya.w + k1*ybv.x + k2*ybv.y + k3*ybv.z + k4*ybv.w;
    st4(&hbX[hr * SW + k * 4], ox);
    st4(&hbY[hr * SW + k * 4], oy);
  }
  __syncthreads();

  // ---- B: vertical blur, both images -> bl[36][68]; zero outside image ----
  for (int g = tid; g < BL_R * 17; g += NT) {
    int br = g / 17, k = g - br * 17, c4 = k * 4;
    bool rok = (unsigned)(base_r + br - 2) < HH;
    int gcb = base_c + c4 - 2;
    bool c0 = rok && (unsigned)(gcb + 0) < WW;
    bool c1 = rok && (unsigned)(gcb + 1) < WW;
    bool c2 = rok && (unsigned)(gcb + 2) < WW;
    bool c3 = rok && (unsigned)(gcb + 3) < WW;
    {
      const float* p = &hbX[br * SW + c4];
      float4 v0 = ld4(p), v1 = ld4(p + SW), v2 = ld4(p + 2*SW),
             v3 = ld4(p + 3*SW), v4 = ld4(p + 4*SW);
      float4 o;
      o.x = c0 ? (k0*v0.x + k1*v1.x + k2*v2.x + k3*v3.x + k4*v4.x) : 0.f;
      o.y = c1 ? (k0*v0.y + k1*v1.y + k2*v2.y + k3*v3.y + k4*v4.y) : 0.f;
      o.z = c2 ? (k0*v0.z + k1*v1.z + k2*v2.z + k3*v3.z + k4*v4.z) : 0.f;
      o.w = c3 ? (k0*v0.w + k1*v1.w + k2*v2.w + k3*v3.w + k4*v4.w) : 0.f;
      st4(&blX[br * SW + c4], o);
    }
    {
      const float* p = &hbY[br * SW + c4];
      float4 v0 = ld4(p), v1 = ld4(p + SW), v2 = ld4(p + 2*SW),
             v3 = ld4(p + 3*SW), v4 = ld4(p + 4*SW);
      float4 o;
      o.x = c0 ? (k0*v0.x + k1*v1.x + k2*v2.x + k3*v3.x + k4*v4.x) : 0.f;
      o.y = c1 ? (k0*v0.y + k1*v1.y + k2*v2.y + k3*v3.y + k4*v4.y) : 0.f;
      o.z = c2 ? (k0*v0.z + k1*v1.z + k2*v2.z + k3*v3.z + k4*v4.z) : 0.f;
      o.w = c3 ? (k0*v0.w + k1*v1.w + k2*v2.w + k3*v3.w + k4*v4.w) : 0.f;
      st4(&blY[br * SW + c4], o);
    }
  }
  __syncthreads();

  // ---- C: sobel magnitude, both images -> mg[34][68] (aliases hb) ----
  for (int g = tid; g < MG_R * 17; g += NT) {
    int mr = g / 17, k = g - mr * 17, c4 = k * 4;
    bool rok = (unsigned)(base_r + mr - 1) < HH;
    int gcb = base_c + c4 - 1;
    {
      const float* p = &blX[mr * SW + c4];
      float4 a0 = ld4(p),          b0 = ld4(p + 4);
      float4 a1 = ld4(p + SW),     b1 = ld4(p + SW + 4);
      float4 a2 = ld4(p + 2*SW),   b2 = ld4(p + 2*SW + 4);
      float e0[6] = {a0.x,a0.y,a0.z,a0.w,b0.x,b0.y};
      float e1[6] = {a1.x,a1.y,a1.z,a1.w,b1.x,b1.y};
      float e2[6] = {a2.x,a2.y,a2.z,a2.w,b2.x,b2.y};
      float4 o; float* po = &o.x;
      #pragma unroll
      for (int j = 0; j < 4; ++j) {
        float gx = (e0[j+2]-e0[j]) + 2.f*(e1[j+2]-e1[j]) + (e2[j+2]-e2[j]);
        float gy = (e2[j]-e0[j]) + 2.f*(e2[j+1]-e0[j+1]) + (e2[j+2]-e0[j+2]);
        float m = sqrtf(gx*gx + gy*gy + 1e-12f);
        po[j] = (rok && (unsigned)(gcb + j) < WW) ? m : 0.f;
      }
      st4(&mgX[mr * SW + c4], o);
    }
    {
      const float* p = &blY[mr * SW + c4];
      float4 a0 = ld4(p),          b0 = ld4(p + 4);
      float4 a1 = ld4(p + SW),     b1 = ld4(p + SW + 4);
      float4 a2 = ld4(p + 2*SW),   b2 = ld4(p + 2*SW + 4);
      float e0[6] = {a0.x,a0.y,a0.z,a0.w,b0.x,b0.y};
      float e1[6] = {a1.x,a1.y,a1.z,a1.w,b1.x,b1.y};
      float e2[6] = {a2.x,a2.y,a2.z,a2.w,b2.x,b2.y};
      float4 o; float* po = &o.x;
      #pragma unroll
      for (int j = 0; j < 4; ++j) {
        float gx = (e0[j+2]-e0[j]) + 2.f*(e1[j+2]-e1[j]) + (e2[j+2]-e2[j]);
        float gy = (e2[j]-e0[j]) + 2.f*(e2[j+1]-e0[j+1]) + (e2[j+2]-e0[j+2]);
        float m = sqrtf(gx*gx + gy*gy + 1e-12f);
        po[j] = (rok && (unsigned)(gcb + j) < WW) ? m : 0.f;
      }
      st4(&mgY[mr * SW + c4], o);
    }
  }
  __syncthreads();

  // ---- D: orientation bin + NMS + loss, column-per-lane (conflict-free) ----
  // Wave wv owns tile rows wv*8..wv*8+7; lane = column. Both images at once.
  float s = 0.f; int so = 0;
  {
    const int lane = tid & 63;
    const int wv   = tid >> 6;
    const int r0   = wv << 3;
    float x00,x01,x02, x10,x11,x12, x20,x21,x22;
    float y00,y01,y02, y10,y11,y12, y20,y21,y22;
    {
      const float* p = &blX[(r0 + 1) * SW + lane + 1];
      x00 = p[0]; x01 = p[1]; x02 = p[2]; p += SW;
      x10 = p[0]; x11 = p[1]; x12 = p[2]; p += SW;
      x20 = p[0]; x21 = p[1]; x22 = p[2];
      const float* q = &blY[(r0 + 1) * SW + lane + 1];
      y00 = q[0]; y01 = q[1]; y02 = q[2]; q += SW;
      y10 = q[0]; y11 = q[1]; y12 = q[2]; q += SW;
      y20 = q[0]; y21 = q[1]; y22 = q[2];
    }
    #pragma unroll
    for (int i = 0; i < 8; ++i) {
      int r = r0 + i;
      int ci = (r + 1) * SW + lane + 1;
      // X image
      float gx = (x02 - x00) + 2.f*(x12 - x10) + (x22 - x20);
      float gy = (x20 - x00) + 2.f*(x21 - x01) + (x22 - x02);
      int rcx = orient_bin(gx, gy);
      int ip = rcx & 7;
      int dr = (int)((DR_PACK >> (2 * ip)) & 3u) - 1;
      int dc = (int)((DC_PACK >> (2 * ip)) & 3u) - 1;
      float mcv = mgX[ci];
      float n1  = mgX[ci + dr * SW + dc];
      float n2  = mgX[ci - dr * SW - dc];
      float thx = (fminf(mcv - n1, mcv - n2) > 0.f) ? mcv : 0.f;
      // Y image
      float hx = (y02 - y00) + 2.f*(y12 - y10) + (y22 - y20);
      float hy = (y20 - y00) + 2.f*(y21 - y01) + (y22 - y02);
      int rcy = orient_bin(hx, hy);
      ip = rcy & 7;
      dr = (int)((DR_PACK >> (2 * ip)) & 3u) - 1;
      dc = (int)((DC_PACK >> (2 * ip)) & 3u) - 1;
      float mcw = mgY[ci];
      float m1  = mgY[ci + dr * SW + dc];
      float m2  = mgY[ci - dr * SW - dc];
      float thy = (fminf(mcw - m1, mcw - m2) > 0.f) ? mcw : 0.f;
      // loss
      s += fabsf(thx - thy);
      so += abs(rcx - rcy);
      if (i < 7) {  // slide both 3x3 windows down one row
        const float* p = &blX[(r + 4) * SW + lane + 1];
        x00 = x10; x01 = x11; x02 = x12;
        x10 = x20; x11 = x21; x12 = x22;
        x20 = p[0]; x21 = p[1]; x22 = p[2];
        const float* q = &blY[(r + 4) * SW + lane + 1];
        y00 = y10; y01 = y11; y02 = y12;
        y10 = y20; y11 = y21; y12 = y22;
        y20 = q[0]; y21 = q[1]; y22 = q[2];
      }
    }
  }
  s += 45.f * (float)so;

  // wave reduce, cross-wave via LDS, one atomic per block
  #pragma unroll
  for (int off = 32; off >= 1; off >>= 1) s += __shfl_down(s, off, 64);
  const int lane = tid & 63, wv = tid >> 6;
  if (lane == 0) red[wv] = s;
  __syncthreads();
  if (tid == 0) {
    float t = red[0] + red[1] + red[2] + red[3];
    atomicAdd(out, t * (1.0f / ((float)HH * (float)WW)));
  }
}

extern "C" void kernel_launch(void* const* d_in, const int* in_sizes, int n_in,
                              void* d_out, int out_size, void* d_ws, size_t ws_size,
                              hipStream_t stream)
{
  const float* X = (const float*)d_in[0];
  const float* Y = (const float*)d_in[1];
  float* out = (float*)d_out;

  hipMemsetAsync(out, 0, (size_t)out_size * sizeof(float), stream);

  // Gaussian 1D weights in double, cast to f32 (matches reference f64->f32 path)
  Blur5 kb;
  {
    double g[5], ssum = 0.0;
    for (int i = 0; i < 5; ++i) { double d = i - 2; g[i] = std::exp(-(d * d) / 2.0); ssum += g[i]; }
    for (int i = 0; i < 5; ++i) kb.w[i] = (float)(g[i] / ssum);
  }

  canny_loss_kernel<<<2048, NT, 0, stream>>>(X, Y, out, kb);
}